// Round 6
// baseline (49.642 us; speedup 1.0000x reference)
//
#include <hip/hip_runtime.h>

// ---------------- problem constants ----------------
constexpr int   kB       = 1024;
constexpr int   kH       = 28;
constexpr int   kW       = 28;
constexpr int   kCells   = kB * kH * kW;        // 802816
constexpr int   kCh      = 30;                  // 10 + 20 classes
constexpr int   kThreads = 256;
constexpr int   kCellsPB = 256;                 // 1 cell per thread (phase 2)
constexpr int   kBlocks  = kCells / kCellsPB;   // 3136
constexpr int   kF4Span  = kCellsPB * kCh / 4;  // 1920 float4 per array per block
constexpr float kLCoord = 5.0f, kLObj = 1.0f, kLNoobj = 0.5f;

__device__ __forceinline__ float iou_decoded(
    float pcx, float pcy, float psw, float psh,
    float tcx, float tcy, float tsw, float tsh)
{
    float aw = tsw * tsw, ah = tsh * tsh;
    float a0 = tcx - aw * 0.5f, a1 = tcy - ah * 0.5f;
    float a2 = tcx + aw * 0.5f, a3 = tcy + ah * 0.5f;
    float bw = psw * psw, bh = psh * psh;
    float b0 = pcx - bw * 0.5f, b1 = pcy - bh * 0.5f;
    float b2 = pcx + bw * 0.5f, b3 = pcy + bh * 0.5f;
    float x0 = fmaxf(a0, b0), y0 = fmaxf(a1, b1);
    float x1 = fminf(a2, b2), y1 = fminf(a3, b3);
    float inter  = fmaxf(x1 - x0, 0.0f) * fmaxf(y1 - y0, 0.0f);
    float area_a = (a2 - a0) * (a3 - a1);
    float area_b = (b2 - b0) * (b3 - b1);
    return inter / (area_a + area_b - inter + 1e-10f);
}

// noobj accumulate for one float4 pair; ch = channel of .x, in [0,30)
__device__ __forceinline__ void neg_accum(const float4& p, const float4& m,
                                          int ch, float& l_neg)
{
    int c = ch;
    { bool sel = (c == 4) | (c == 9); float d = p.x - m.x;
      l_neg += (sel && (m.x < 1.0f)) ? d * d : 0.0f; }
    c = (c == 29) ? 0 : c + 1;
    { bool sel = (c == 4) | (c == 9); float d = p.y - m.y;
      l_neg += (sel && (m.y < 1.0f)) ? d * d : 0.0f; }
    c = (c == 29) ? 0 : c + 1;
    { bool sel = (c == 4) | (c == 9); float d = p.z - m.z;
      l_neg += (sel && (m.z < 1.0f)) ? d * d : 0.0f; }
    c = (c == 29) ? 0 : c + 1;
    { bool sel = (c == 4) | (c == 9); float d = p.w - m.w;
      l_neg += (sel && (m.w < 1.0f)) ? d * d : 0.0f; }
}

// ws layout: ws[m*kBlocks + b], m: 0=cls 1=resp 2=off 3=neg (unscaled sums)
__global__ __launch_bounds__(256, 6) void yolo_loss_main(
    const float* __restrict__ pred, const float* __restrict__ meta,
    float* __restrict__ ws)
{
    const int t  = threadIdx.x;
    const int c0 = blockIdx.x * kCellsPB;

    // ===== phase 1: coalesced float4 stream over the block span =====
    // Span: 256 cells * 30 floats = 7680 floats = 1920 float4 per array
    // (base = bid*30720 B, 16B-aligned). Thread t reads j = t + 256*i,
    // i=0..6 full + tail i=7 for t<128. Channel of .x: (4*j) mod 30;
    // stride 256 float4 => +4 (mod 30) per iteration.
    float l_neg = 0.0f;
    {
        const size_t fbase = (size_t)c0 * kCh;
        const float4* p4p = reinterpret_cast<const float4*>(pred + fbase);
        const float4* m4p = reinterpret_cast<const float4*>(meta + fbase);

        int ch = (4 * t) % 30;
        #pragma unroll
        for (int i = 0; i < 7; ++i) {
            const int j = t + kThreads * i;
            float4 p = p4p[j];
            float4 m = m4p[j];
            neg_accum(p, m, ch, l_neg);
            ch += 4; if (ch >= 30) ch -= 30;
        }
        if (t < kF4Span - 7 * kThreads) {   // tail: 128 threads
            const int j = t + 7 * kThreads;
            float4 p = p4p[j];
            float4 m = m4p[j];
            neg_accum(p, m, ch, l_neg);
        }
    }

    // ===== phase 2: this thread's cell, positive path only (~2%); L1/L2-hot =====
    float l_cls = 0.0f, l_resp = 0.0f, l_off = 0.0f;
    {
        const int cg = c0 + t;
        const float* pc = pred + (size_t)cg * kCh;
        const float* mc = meta + (size_t)cg * kCh;
        float resp = mc[4];                      // just streamed -> cache hit
        if (resp + resp > 0.9f) {
            // boxes: ch0..9 as 5 aligned float2 each (cell base is 8B-aligned)
            const float2* pp = reinterpret_cast<const float2*>(pc);
            const float2* mm = reinterpret_cast<const float2*>(mc);
            float2 pa0 = pp[0], pa1 = pp[1], pa2 = pp[2], pa3 = pp[3], pa4 = pp[4];
            float2 ma0 = mm[0], ma1 = mm[1], ma2 = mm[2], ma3 = mm[3], ma4 = mm[4];

            float iou0 = iou_decoded(pa0.x, pa0.y, pa1.x, pa1.y,
                                     ma0.x, ma0.y, ma1.x, ma1.y);
            float iou1 = iou_decoded(pa2.y, pa3.x, pa3.y, pa4.x,
                                     ma2.y, ma3.x, ma3.y, ma4.x);
            float off0 = (pa0.x - ma0.x) * (pa0.x - ma0.x)
                       + (pa0.y - ma0.y) * (pa0.y - ma0.y)
                       + (pa1.x - ma1.x) * (pa1.x - ma1.x)
                       + (pa1.y - ma1.y) * (pa1.y - ma1.y);
            float off1 = (pa2.y - ma2.y) * (pa2.y - ma2.y)
                       + (pa3.x - ma3.x) * (pa3.x - ma3.x)
                       + (pa3.y - ma3.y) * (pa3.y - ma3.y)
                       + (pa4.x - ma4.x) * (pa4.x - ma4.x);
            float p4v = pa2.x;   // pred ch4
            float p9v = pa4.y;   // pred ch9

            bool best1 = (iou1 > iou0);          // first-max tie-break => strict >
            float iou_b    = best1 ? iou1 : iou0;
            float p_resp_b = best1 ? p9v  : p4v;
            float dr = p_resp_b - iou_b;
            l_resp = dr * dr;                    // pos==1 here
            l_off  = best1 ? off1 : off0;

            // class loss: ch10..29 as 10 aligned float2 each
            float cls_acc = 0.0f;
            const float2* pcl = reinterpret_cast<const float2*>(pc + 10);
            const float2* mcl = reinterpret_cast<const float2*>(mc + 10);
            #pragma unroll
            for (int i = 0; i < 10; ++i) {
                float2 a = pcl[i], b = mcl[i];
                float d0 = a.x - b.x, d1 = a.y - b.y;
                cls_acc += d0 * d0 + d1 * d1;
            }
            l_cls = cls_acc;
            // noobj for this cell already covered by phase 1 (mask resp<1 false)
        }
    }

    // ===== reduction: wave shuffle -> LDS -> per-block stores =====
    #pragma unroll
    for (int off = 32; off > 0; off >>= 1) {
        l_cls  += __shfl_down(l_cls,  off);
        l_resp += __shfl_down(l_resp, off);
        l_off  += __shfl_down(l_off,  off);
        l_neg  += __shfl_down(l_neg,  off);
    }

    __shared__ float red[4][4];  // [metric][wave]
    const int lane = t & 63;
    const int wid  = t >> 6;
    if (lane == 0) {
        red[0][wid] = l_cls;
        red[1][wid] = l_resp;
        red[2][wid] = l_off;
        red[3][wid] = l_neg;
    }
    __syncthreads();
    if (t == 0) {
        const int b = blockIdx.x;
        ws[0 * kBlocks + b] = red[0][0] + red[0][1] + red[0][2] + red[0][3];
        ws[1 * kBlocks + b] = red[1][0] + red[1][1] + red[1][2] + red[1][3];
        ws[2 * kBlocks + b] = red[2][0] + red[2][1] + red[2][2] + red[2][3];
        ws[3 * kBlocks + b] = red[3][0] + red[3][1] + red[3][2] + red[3][3];
    }
}

// Single-block deterministic reduce of the 4 x 3136 partials + finalize.
// out: (loss_sum, loss_pos_response, loss_neg_response, loss_pos_cls, loss_pos_offset)
__global__ __launch_bounds__(1024) void yolo_loss_reduce(
    const float* __restrict__ ws, float* __restrict__ out)
{
    const int t = threadIdx.x;
    float acc[4] = {0.0f, 0.0f, 0.0f, 0.0f};
    #pragma unroll
    for (int m = 0; m < 4; ++m) {
        for (int i = t; i < kBlocks; i += 1024) {   // coalesced
            acc[m] += ws[m * kBlocks + i];
        }
    }
    #pragma unroll
    for (int off = 32; off > 0; off >>= 1) {
        acc[0] += __shfl_down(acc[0], off);
        acc[1] += __shfl_down(acc[1], off);
        acc[2] += __shfl_down(acc[2], off);
        acc[3] += __shfl_down(acc[3], off);
    }
    __shared__ float red[4][16];
    const int lane = t & 63;
    const int wid  = t >> 6;
    if (lane == 0) {
        red[0][wid] = acc[0];
        red[1][wid] = acc[1];
        red[2][wid] = acc[2];
        red[3][wid] = acc[3];
    }
    __syncthreads();
    if (t == 0) {
        float s[4];
        #pragma unroll
        for (int m = 0; m < 4; ++m) {
            float v = 0.0f;
            #pragma unroll
            for (int w = 0; w < 16; ++w) v += red[m][w];
            s[m] = v;
        }
        float inv_b  = 1.0f / (float)kB;
        float s_cls  = s[0] * inv_b;
        float s_resp = s[1] * inv_b * kLObj;
        float s_off  = s[2] * inv_b * kLCoord;
        float s_neg  = s[3] * inv_b * kLNoobj;
        out[0] = s_neg + s_resp + s_off + s_cls;  // reference addition order
        out[1] = s_resp;
        out[2] = s_neg;
        out[3] = s_cls;
        out[4] = s_off;
    }
}

extern "C" void kernel_launch(void* const* d_in, const int* in_sizes, int n_in,
                              void* d_out, int out_size, void* d_ws, size_t ws_size,
                              hipStream_t stream) {
    const float* pred = (const float*)d_in[0];
    const float* meta = (const float*)d_in[1];
    float* out = (float*)d_out;
    float* ws  = (float*)d_ws;

    // No ws zeroing needed: every ws slot [0, 4*kBlocks) is written by main.
    yolo_loss_main<<<kBlocks, kThreads, 0, stream>>>(pred, meta, ws);
    yolo_loss_reduce<<<1, 1024, 0, stream>>>(ws, out);
}

// Round 7
// 39.827 us; speedup vs baseline: 1.2464x; 1.2464x over previous
//
#include <hip/hip_runtime.h>

// ---------------- problem constants ----------------
constexpr int   kB       = 1024;
constexpr int   kH       = 28;
constexpr int   kW       = 28;
constexpr int   kCells   = kB * kH * kW;        // 802816
constexpr int   kCh      = 30;                  // 10 + 20 classes
constexpr int   kThreads = 256;
constexpr int   kCPT     = 2;                   // cells per thread
constexpr int   kCellsPB = kThreads * kCPT;     // 512
constexpr int   kBlocks  = kCells / kCellsPB;   // 1568
constexpr float kLCoord = 5.0f, kLObj = 1.0f, kLNoobj = 0.5f;

__device__ __forceinline__ float iou_decoded(
    float pcx, float pcy, float psw, float psh,
    float tcx, float tcy, float tsw, float tsh)
{
    float aw = tsw * tsw, ah = tsh * tsh;
    float a0 = tcx - aw * 0.5f, a1 = tcy - ah * 0.5f;
    float a2 = tcx + aw * 0.5f, a3 = tcy + ah * 0.5f;
    float bw = psw * psw, bh = psh * psh;
    float b0 = pcx - bw * 0.5f, b1 = pcy - bh * 0.5f;
    float b2 = pcx + bw * 0.5f, b3 = pcy + bh * 0.5f;
    float x0 = fmaxf(a0, b0), y0 = fmaxf(a1, b1);
    float x1 = fminf(a2, b2), y1 = fminf(a3, b3);
    float inter  = fmaxf(x1 - x0, 0.0f) * fmaxf(y1 - y0, 0.0f);
    float area_a = (a2 - a0) * (a3 - a1);
    float area_b = (b2 - b0) * (b3 - b1);
    return inter / (area_a + area_b - inter + 1e-10f);
}

// Full positive-cell computation (pos==1 guaranteed by caller).
__device__ __forceinline__ void positive_cell(
    const float* __restrict__ pc, const float* __restrict__ mc,
    float& l_cls, float& l_resp, float& l_off)
{
    // boxes: ch0..9 as 5 aligned float2 each (cell base is 8B-aligned)
    const float2* pp = reinterpret_cast<const float2*>(pc);
    const float2* mm = reinterpret_cast<const float2*>(mc);
    float2 pa0 = pp[0], pa1 = pp[1], pa2 = pp[2], pa3 = pp[3], pa4 = pp[4];
    float2 ma0 = mm[0], ma1 = mm[1], ma2 = mm[2], ma3 = mm[3], ma4 = mm[4];

    float iou0 = iou_decoded(pa0.x, pa0.y, pa1.x, pa1.y,
                             ma0.x, ma0.y, ma1.x, ma1.y);
    float iou1 = iou_decoded(pa2.y, pa3.x, pa3.y, pa4.x,
                             ma2.y, ma3.x, ma3.y, ma4.x);
    float off0 = (pa0.x - ma0.x) * (pa0.x - ma0.x)
               + (pa0.y - ma0.y) * (pa0.y - ma0.y)
               + (pa1.x - ma1.x) * (pa1.x - ma1.x)
               + (pa1.y - ma1.y) * (pa1.y - ma1.y);
    float off1 = (pa2.y - ma2.y) * (pa2.y - ma2.y)
               + (pa3.x - ma3.x) * (pa3.x - ma3.x)
               + (pa3.y - ma3.y) * (pa3.y - ma3.y)
               + (pa4.x - ma4.x) * (pa4.x - ma4.x);
    float p4v = pa2.x;   // pred ch4
    float p9v = pa4.y;   // pred ch9

    bool best1 = (iou1 > iou0);          // first-max tie-break => strict >
    float iou_b    = best1 ? iou1 : iou0;
    float p_resp_b = best1 ? p9v  : p4v;
    float dr = p_resp_b - iou_b;
    l_resp += dr * dr;
    l_off  += best1 ? off1 : off0;

    // class loss: ch10..29 as 10 aligned float2 each
    float cls_acc = 0.0f;
    const float2* pcl = reinterpret_cast<const float2*>(pc + 10);
    const float2* mcl = reinterpret_cast<const float2*>(mc + 10);
    #pragma unroll
    for (int i = 0; i < 10; ++i) {
        float2 a = pcl[i], b = mcl[i];
        float d0 = a.x - b.x, d1 = a.y - b.y;
        cls_acc += d0 * d0 + d1 * d1;
    }
    l_cls += cls_acc;
}

// ws layout: ws[m*kBlocks + b], m: 0=cls 1=resp 2=off 3=neg (unscaled sums)
__global__ __launch_bounds__(256) void yolo_loss_main(
    const float* __restrict__ pred, const float* __restrict__ meta,
    float* __restrict__ ws)
{
    const int t  = threadIdx.x;
    const int c0 = blockIdx.x * kCellsPB;

    // Two cells per thread, adjacent waves' lanes stay contiguous per batch.
    const int cgA = c0 + t;
    const int cgB = c0 + t + kThreads;
    const float* pcA = pred + (size_t)cgA * kCh;
    const float* mcA = meta + (size_t)cgA * kCh;
    const float* pcB = pred + (size_t)cgB * kCh;
    const float* mcB = meta + (size_t)cgB * kCh;

    // ---- issue all 6 independent classification loads up front (MLP) ----
    float respA = mcA[4];
    float p4A   = pcA[4];
    float p9A   = pcA[9];
    float respB = mcB[4];
    float p4B   = pcB[4];
    float p9B   = pcB[9];

    // ---- element-local noobj (resp==1 cells masked out: resp<1 false) ----
    float l_neg = 0.0f;
    {
        float nA = (respA < 1.0f) ? 1.0f : 0.0f;
        float d0 = p4A - respA, d1 = p9A - respA;
        l_neg += nA * (d0 * d0 + d1 * d1);
        float nB = (respB < 1.0f) ? 1.0f : 0.0f;
        float e0 = p4B - respB, e1 = p9B - respB;
        l_neg += nB * (e0 * e0 + e1 * e1);
    }

    // ---- positive paths (~2% of cells) ----
    float l_cls = 0.0f, l_resp = 0.0f, l_off = 0.0f;
    if (respA > 0.45f) positive_cell(pcA, mcA, l_cls, l_resp, l_off);
    if (respB > 0.45f) positive_cell(pcB, mcB, l_cls, l_resp, l_off);

    // ---- hierarchical reduction: wave shuffle -> LDS -> per-block stores ----
    #pragma unroll
    for (int off = 32; off > 0; off >>= 1) {
        l_cls  += __shfl_down(l_cls,  off);
        l_resp += __shfl_down(l_resp, off);
        l_off  += __shfl_down(l_off,  off);
        l_neg  += __shfl_down(l_neg,  off);
    }

    __shared__ float red[4][4];  // [metric][wave]
    const int lane = t & 63;
    const int wid  = t >> 6;
    if (lane == 0) {
        red[0][wid] = l_cls;
        red[1][wid] = l_resp;
        red[2][wid] = l_off;
        red[3][wid] = l_neg;
    }
    __syncthreads();
    if (t == 0) {
        const int b = blockIdx.x;
        ws[0 * kBlocks + b] = red[0][0] + red[0][1] + red[0][2] + red[0][3];
        ws[1 * kBlocks + b] = red[1][0] + red[1][1] + red[1][2] + red[1][3];
        ws[2 * kBlocks + b] = red[2][0] + red[2][1] + red[2][2] + red[2][3];
        ws[3 * kBlocks + b] = red[3][0] + red[3][1] + red[3][2] + red[3][3];
    }
}

// Single-block deterministic reduce of the 4 x 1568 partials + finalize.
// out: (loss_sum, loss_pos_response, loss_neg_response, loss_pos_cls, loss_pos_offset)
__global__ __launch_bounds__(1024) void yolo_loss_reduce(
    const float* __restrict__ ws, float* __restrict__ out)
{
    const int t = threadIdx.x;
    float acc[4] = {0.0f, 0.0f, 0.0f, 0.0f};
    #pragma unroll
    for (int m = 0; m < 4; ++m) {
        for (int i = t; i < kBlocks; i += 1024) {   // coalesced
            acc[m] += ws[m * kBlocks + i];
        }
    }
    #pragma unroll
    for (int off = 32; off > 0; off >>= 1) {
        acc[0] += __shfl_down(acc[0], off);
        acc[1] += __shfl_down(acc[1], off);
        acc[2] += __shfl_down(acc[2], off);
        acc[3] += __shfl_down(acc[3], off);
    }
    __shared__ float red[4][16];
    const int lane = t & 63;
    const int wid  = t >> 6;
    if (lane == 0) {
        red[0][wid] = acc[0];
        red[1][wid] = acc[1];
        red[2][wid] = acc[2];
        red[3][wid] = acc[3];
    }
    __syncthreads();
    if (t == 0) {
        float s[4];
        #pragma unroll
        for (int m = 0; m < 4; ++m) {
            float v = 0.0f;
            #pragma unroll
            for (int w = 0; w < 16; ++w) v += red[m][w];
            s[m] = v;
        }
        float inv_b  = 1.0f / (float)kB;
        float s_cls  = s[0] * inv_b;
        float s_resp = s[1] * inv_b * kLObj;
        float s_off  = s[2] * inv_b * kLCoord;
        float s_neg  = s[3] * inv_b * kLNoobj;
        out[0] = s_neg + s_resp + s_off + s_cls;  // reference addition order
        out[1] = s_resp;
        out[2] = s_neg;
        out[3] = s_cls;
        out[4] = s_off;
    }
}

extern "C" void kernel_launch(void* const* d_in, const int* in_sizes, int n_in,
                              void* d_out, int out_size, void* d_ws, size_t ws_size,
                              hipStream_t stream) {
    const float* pred = (const float*)d_in[0];
    const float* meta = (const float*)d_in[1];
    float* out = (float*)d_out;
    float* ws  = (float*)d_ws;

    // No ws zeroing needed: every ws slot [0, 4*kBlocks) is written by main.
    yolo_loss_main<<<kBlocks, kThreads, 0, stream>>>(pred, meta, ws);
    yolo_loss_reduce<<<1, 1024, 0, stream>>>(ws, out);
}